// Round 2
// baseline (211.998 us; speedup 1.0000x reference)
//
#include <hip/hip_runtime.h>
#include <hip/hip_bf16.h>
#include <stdint.h>

// Problem constants (B,S,I fixed by setup_inputs)
#define B_DIM 8
#define S_DIM 4096
#define I_DIM 256
#define M_DIM (B_DIM * S_DIM)   // 32768 rows
#define N_DIM 1536              // 6*OUT gate columns
#define K_DIM 512               // WINDOW*I

// GEMM tiling
#define TM 128
#define TN 128
#define BK 64

typedef __attribute__((ext_vector_type(8))) short bf16x8;   // 8 bf16 in 4 VGPRs
typedef __attribute__((ext_vector_type(4))) float f32x4;

typedef const void __attribute__((address_space(1)))* gas_ptr;
typedef void __attribute__((address_space(3)))* las_ptr;

__device__ __forceinline__ void gload_lds16(const void* g, void* l) {
    // async global->LDS, 16B/lane; LDS dest = wave-uniform base + lane*16
    __builtin_amdgcn_global_load_lds((gas_ptr)(uintptr_t)g, (las_ptr)(uintptr_t)l, 16, 0, 0);
}

__device__ __forceinline__ float fast_sigmoid(float x) {
    // overflow-safe: exp(-x) -> inf gives 1/(1+inf)=0 (correct limit)
    return 1.0f / (1.0f + __expf(-x));
}
__device__ __forceinline__ float fast_tanh(float x) {
    // exp of non-positive arg only -> never overflows
    float ax = fabsf(x);
    float e = __expf(-2.0f * ax);
    float t = (1.0f - e) / (1.0f + e);
    return copysignf(t, x);
}

__device__ __forceinline__ unsigned short f2bf(float f) {
    // round-to-nearest-even fp32 -> bf16 (values here are finite/normal)
    uint32_t u = __float_as_uint(f);
    uint32_t r = (u + 0x7FFFu + ((u >> 16) & 1u)) >> 16;
    return (unsigned short)r;
}

// ---------------------------------------------------------------------------
// fp32 -> bf16 conversion (4 elems/thread, float4 in, ushort4 out)
// also zero-inits the zero page (flag)
// ---------------------------------------------------------------------------
__global__ __launch_bounds__(256)
void cvt_f32_bf16(const float* __restrict__ in, unsigned short* __restrict__ out,
                  int n4, unsigned short* __restrict__ zp)
{
    int i = blockIdx.x * 256 + threadIdx.x;
    if (zp && blockIdx.x == 0 && threadIdx.x < 64) zp[threadIdx.x] = 0;
    if (i < n4) {
        float4 v = ((const float4*)in)[i];
        ushort4 o;
        o.x = f2bf(v.x); o.y = f2bf(v.y); o.z = f2bf(v.z); o.w = f2bf(v.w);
        ((ushort4*)out)[i] = o;
    }
}

// ---------------------------------------------------------------------------
// Kernel 1: fused windowed GEMM + bias + gate activations
// gact[m][col] (bf16), col = gate*512 + dir*256 + oo
//   gate 0 -> tanh(z), gate 1 -> sigmoid(f), gate 2 -> sigmoid(o)
// A[m][k] = (k<256) ? x[b, s-1, k] (0 if s==0) : x[b, s, k-256]
// ---------------------------------------------------------------------------
__global__ __launch_bounds__(256, 2)
void qrnn_gemm(const __hip_bfloat16* __restrict__ x,
               const __hip_bfloat16* __restrict__ W,
               const float* __restrict__ bias,
               __hip_bfloat16* __restrict__ gact,
               const __hip_bfloat16* __restrict__ zeroPage)
{
    __shared__ __hip_bfloat16 lA[TM * BK];   // 16 KB, XOR-8 swizzled chunks of 8 elems
    __shared__ __hip_bfloat16 lB[TN * BK];   // 16 KB

    const int tid = threadIdx.x;
    const int w = tid >> 6;        // wave 0..3
    const int l = tid & 63;        // lane

    const int tileM = blockIdx.x & 255;   // 256 M-tiles
    const int tileN = blockIdx.x >> 8;    // 12 N-tiles
    const int m0 = tileM * TM;
    const int n0 = tileN * TN;
    const int bIdx = m0 >> 12;            // batch (tiles never straddle b: 4096 % 128 == 0)
    const int sBase = m0 & 4095;

    // staging: lane l fills LDS slot (row rowInP, chunk slot l&7) which must
    // hold global chunk (l&7) ^ (row&7)  [XOR-8 swizzle, row&7 == (l>>3)&7]
    const int c8 = (l & 7) ^ ((l >> 3) & 7);
    const int rowInP = w * 8 + (l >> 3);

    // fragment lane constants
    const int la = l & 15, lq = l >> 4;
    const int wm = w >> 1, wn = w & 1;

    f32x4 acc[4][4] = {};

    for (int kt = 0; kt < K_DIM / BK; ++kt) {
        __syncthreads();   // protect LDS from readers of previous iteration
        const int kcol = kt * 64 + c8 * 8;
#pragma unroll
        for (int p = 0; p < 4; ++p) {
            const int r = p * 32 + rowInP;
            // ---- A tile: windowed x ----
            const int srow = sBase + r;
            const __hip_bfloat16* srcA;
            if (kcol < 256) {
                srcA = (srow == 0) ? zeroPage
                     : x + ((size_t)((bIdx << 12) + srow - 1) * 256 + kcol);
            } else {
                srcA = x + ((size_t)((bIdx << 12) + srow) * 256 + (kcol - 256));
            }
            gload_lds16(srcA, &lA[p * 2048 + w * 512]);
            // ---- B tile: W rows (N-major, K contiguous) ----
            const int nrow = n0 + r;
            gload_lds16(W + ((size_t)nrow * 512 + kcol), &lB[p * 2048 + w * 512]);
        }
        __syncthreads();   // drains vmcnt for global_load_lds

#pragma unroll
        for (int kk = 0; kk < 2; ++kk) {
            bf16x8 af[4], bfr[4];
#pragma unroll
            for (int i = 0; i < 4; ++i) {
                const int ra = wm * 64 + i * 16 + la;
                const int ch = (kk * 4 + lq) ^ (ra & 7);
                af[i] = *(const bf16x8*)&lA[ra * 64 + ch * 8];
            }
#pragma unroll
            for (int j = 0; j < 4; ++j) {
                const int rb = wn * 64 + j * 16 + la;
                const int ch = (kk * 4 + lq) ^ (rb & 7);
                bfr[j] = *(const bf16x8*)&lB[rb * 64 + ch * 8];
            }
#pragma unroll
            for (int i = 0; i < 4; ++i)
#pragma unroll
                for (int j = 0; j < 4; ++j)
                    acc[i][j] = __builtin_amdgcn_mfma_f32_16x16x32_bf16(
                        af[i], bfr[j], acc[i][j], 0, 0, 0);
        }
    }

    // epilogue: C/D layout col=lane&15, row=(lane>>4)*4+reg (guide §3, m89-verified)
    const int gate = n0 >> 9;   // block-uniform: 0=z, 1=f, 2=o
#pragma unroll
    for (int i = 0; i < 4; ++i) {
        const int mrow = m0 + wm * 64 + i * 16 + lq * 4;
#pragma unroll
        for (int j = 0; j < 4; ++j) {
            const int col = n0 + wn * 64 + j * 16 + la;
            const float bv = bias[col];
#pragma unroll
            for (int rr = 0; rr < 4; ++rr) {
                float v = acc[i][j][rr] + bv;
                float a = (gate == 0) ? fast_tanh(v) : fast_sigmoid(v);
                gact[(size_t)(mrow + rr) * N_DIM + col] = __float2bfloat16(a);
            }
        }
    }
}

// ---------------------------------------------------------------------------
// Chunked linear-recurrence scan: c[t] = f*c_prev + (1-f)*z (per dir)
// N_seq = 4096 sequences (b,dir,oo), S=4096, chunks of 64.
// ---------------------------------------------------------------------------
#define NCHUNK 64
#define CLEN 64
#define NSEQ 4096

__global__ __launch_bounds__(256)
void qrnn_scanA(const __hip_bfloat16* __restrict__ gact,
                float* __restrict__ cA, float* __restrict__ cB)
{
    const int oo = threadIdx.x;
    const int bid = blockIdx.x;           // 1024 = b*2*NCHUNK
    const int chunk = bid & 63;
    const int dir = (bid >> 6) & 1;
    const int b = bid >> 7;
    const int zc = dir * 256 + oo;
    const int t0 = chunk * CLEN;

    float A = 1.0f, Bv = 0.0f;
#pragma unroll 4
    for (int tt = 0; tt < CLEN; ++tt) {
        const int t = dir ? (t0 + CLEN - 1 - tt) : (t0 + tt);
        const size_t off = ((size_t)(b * S_DIM + t)) * N_DIM;
        const float z = __bfloat162float(gact[off + zc]);
        const float f = __bfloat162float(gact[off + 512 + zc]);
        Bv = f * Bv + (1.0f - f) * z;
        A *= f;
    }
    const int seq = (b * 2 + dir) * 256 + oo;
    cA[chunk * NSEQ + seq] = A;
    cB[chunk * NSEQ + seq] = Bv;
}

__global__ __launch_bounds__(256)
void qrnn_scanB(const float* __restrict__ cA, const float* __restrict__ cB,
                float* __restrict__ carry)
{
    const int seq = blockIdx.x * 256 + threadIdx.x;   // 16 blocks
    const int dir = (seq >> 8) & 1;
    float c = 0.0f;
    if (dir == 0) {
#pragma unroll 4
        for (int ch = 0; ch < NCHUNK; ++ch) {
            carry[ch * NSEQ + seq] = c;
            c = cA[ch * NSEQ + seq] * c + cB[ch * NSEQ + seq];
        }
    } else {
#pragma unroll 4
        for (int ch = NCHUNK - 1; ch >= 0; --ch) {
            carry[ch * NSEQ + seq] = c;
            c = cA[ch * NSEQ + seq] * c + cB[ch * NSEQ + seq];
        }
    }
}

__global__ __launch_bounds__(256)
void qrnn_scanC(const __hip_bfloat16* __restrict__ gact,
                const float* __restrict__ carry,
                float* __restrict__ out)
{
    const int oo = threadIdx.x;
    const int bid = blockIdx.x;
    const int chunk = bid & 63;
    const int dir = (bid >> 6) & 1;
    const int b = bid >> 7;
    const int zc = dir * 256 + oo;
    const int seq = (b * 2 + dir) * 256 + oo;
    const int t0 = chunk * CLEN;

    float c = carry[chunk * NSEQ + seq];
#pragma unroll 4
    for (int tt = 0; tt < CLEN; ++tt) {
        const int t = dir ? (t0 + CLEN - 1 - tt) : (t0 + tt);
        const size_t row = (size_t)(b * S_DIM + t);
        const size_t off = row * N_DIM;
        const float z = __bfloat162float(gact[off + zc]);
        const float f = __bfloat162float(gact[off + 512 + zc]);
        const float o = __bfloat162float(gact[off + 1024 + zc]);
        c = f * c + (1.0f - f) * z;
        out[row * 512 + zc] = o * c;
    }
}

// ---------------------------------------------------------------------------
extern "C" void kernel_launch(void* const* d_in, const int* in_sizes, int n_in,
                              void* d_out, int out_size, void* d_ws, size_t ws_size,
                              hipStream_t stream)
{
    const float* x    = (const float*)d_in[0];   // (8,4096,256) fp32
    const float* W    = (const float*)d_in[1];   // (1536,512)  fp32
    const float* bias = (const float*)d_in[2];   // (1536,)     fp32
    float* out = (float*)d_out;                  // (8,4096,512) fp32

    char* ws = (char*)d_ws;
    size_t off = 0;
    __hip_bfloat16* xb   = (__hip_bfloat16*)(ws + off); off += (size_t)M_DIM * I_DIM * 2;      // 16.8 MB
    __hip_bfloat16* Wb   = (__hip_bfloat16*)(ws + off); off += (size_t)N_DIM * K_DIM * 2;      // 1.5 MB
    __hip_bfloat16* gact = (__hip_bfloat16*)(ws + off); off += (size_t)M_DIM * N_DIM * 2;      // 100.7 MB
    float* cA    = (float*)(ws + off); off += (size_t)NSEQ * NCHUNK * 4;   // 1 MB
    float* cB    = (float*)(ws + off); off += (size_t)NSEQ * NCHUNK * 4;   // 1 MB
    float* carry = (float*)(ws + off); off += (size_t)NSEQ * NCHUNK * 4;   // 1 MB
    unsigned short* zeroPage = (unsigned short*)(ws + off); off += 128;

    const int nx4 = (M_DIM * I_DIM) / 4;   // 2,097,152
    const int nw4 = (N_DIM * K_DIM) / 4;   //   196,608
    cvt_f32_bf16<<<dim3((nx4 + 255) / 256), dim3(256), 0, stream>>>(x, (unsigned short*)xb, nx4, zeroPage);
    cvt_f32_bf16<<<dim3((nw4 + 255) / 256), dim3(256), 0, stream>>>(W, (unsigned short*)Wb, nw4, nullptr);

    qrnn_gemm<<<dim3(256 * 12), dim3(256), 0, stream>>>(xb, Wb, bias, gact,
                                                        (const __hip_bfloat16*)zeroPage);
    qrnn_scanA<<<dim3(B_DIM * 2 * NCHUNK), dim3(256), 0, stream>>>(gact, cA, cB);
    qrnn_scanB<<<dim3(NSEQ / 256), dim3(256), 0, stream>>>(cA, cB, carry);
    qrnn_scanC<<<dim3(B_DIM * 2 * NCHUNK), dim3(256), 0, stream>>>(gact, carry, out);
}